// Round 10
// baseline (213.070 us; speedup 1.0000x reference)
//
#include <hip/hip_runtime.h>
#include <hip/hip_fp16.h>
#include <math.h>

#define NUM_CLASSES 10

// Bucketed CSR build parameters (128 nodes/bucket -> 782 buckets) [R7 proven]
#define BSH 7
#define BSZ 128            // nodes per bucket
#define BCAP 1792          // max edges per bucket (mean ~1280, sigma ~36; +14 sigma)
#define NBMAX 1024         // static LDS histogram capacity
#define P1BATCH 2048       // edges per p1-role block (8/thread; R10: isolate batch var)
#define PREPB 97           // prep-role blocks in the merged kernel

typedef _Float16 half8  __attribute__((ext_vector_type(8)));
typedef _Float16 half4t __attribute__((ext_vector_type(4)));
typedef float    floatx4 __attribute__((ext_vector_type(4)));

// Fire-and-forget 16B global->LDS DMA (no VGPR round-trip). Lane i of the
// wave writes lds_base + i*16; global src is per-lane. Drained by the
// vmcnt(0) the compiler emits before the next __syncthreads().
__device__ __forceinline__ void gload_lds16(const void* g, void* l) {
    __builtin_amdgcn_global_load_lds(
        (const __attribute__((address_space(1))) unsigned int*)g,
        (__attribute__((address_space(3))) unsigned int*)l, 16, 0, 0);
}

// ---------------------------------------------------------------------------
// Merged prep + CSR pass 1 (direct scatter, 12 KB LDS — R7 geometry).
// R10: P1BATCH 2048 -> 489 p1-role blocks (~1.9/CU, was 0.96/CU). R8's
// regression confounded this with the bucket-size change; this round tests
// the batch variable alone. int4-vectorized ingest kept from R9.
// ---------------------------------------------------------------------------
__global__ __launch_bounds__(256) void prep_p1_kernel(const float* __restrict__ W1,
                                                      const float* __restrict__ W2,
                                                      const float* __restrict__ Wlc,
                                                      _Float16* __restrict__ W1t,
                                                      _Float16* __restrict__ W2t,
                                                      _Float16* __restrict__ Wct,
                                                      const int* __restrict__ src,
                                                      const int* __restrict__ dst,
                                                      int* __restrict__ bucket_fill,
                                                      unsigned* __restrict__ pairs, int E) {
    __shared__ int hist[NBMAX], base[NBMAX], cur[NBMAX];   // 12 KB
    const int tid = threadIdx.x;
    const int b = blockIdx.x;

    if (b < PREPB) {
        if (b < 32) {
            int i = b * 256 + tid;            // 8192 = 64*128
            int k = i >> 7, c = i & 127;
            W1t[c * 72 + k] = (_Float16)W1[i];
        } else if (b < 96) {
            int i = (b - 32) * 256 + tid;     // 16384 = 128*128
            int k = i >> 7, c = i & 127;
            W2t[c * 136 + k] = (_Float16)W2[i];
        } else {
            for (int i = tid; i < 16 * 136; i += 256) {
                int c = i / 136, k = i - c * 136;
                float v = (c < NUM_CLASSES && k < 128) ? Wlc[k * NUM_CLASSES + c] : 0.0f;
                Wct[i] = (_Float16)v;
            }
        }
        return;
    }

    for (int i = tid; i < NBMAX; i += 256) { hist[i] = 0; cur[i] = 0; }
    __syncthreads();
    const int bb = (b - PREPB) * P1BATCH;
    const int4* src4 = (const int4*)src;
    const int4* dst4 = (const int4*)dst;
    const bool v4ok = ((E & 3) == 0);
    unsigned pk[8];
    int bk[8];
    int cnt = 0;
#pragma unroll
    for (int j = 0; j < 2; ++j) {
        const int g4 = (bb >> 2) + j * 256 + tid;
        const int base4 = g4 << 2;
        if (v4ok && base4 + 3 < E) {
            const int4 s4 = src4[g4];
            const int4 d4 = dst4[g4];
            const int ss[4] = {s4.x, s4.y, s4.z, s4.w};
            const int dd[4] = {d4.x, d4.y, d4.z, d4.w};
#pragma unroll
            for (int u = 0; u < 4; ++u) {
                bk[j * 4 + u] = dd[u] >> BSH;
                pk[j * 4 + u] = ((unsigned)ss[u] << BSH) | (unsigned)(dd[u] & (BSZ - 1));
                atomicAdd(&hist[bk[j * 4 + u]], 1);
            }
            cnt = j * 4 + 4;
        } else {
#pragma unroll
            for (int u = 0; u < 4; ++u) {
                const int idx = base4 + u;
                if (idx < E) {
                    int s = src[idx], d = dst[idx];
                    bk[j * 4 + u] = d >> BSH;
                    pk[j * 4 + u] = ((unsigned)s << BSH) | (unsigned)(d & (BSZ - 1));
                    atomicAdd(&hist[bk[j * 4 + u]], 1);
                    cnt = j * 4 + u + 1;
                }
            }
        }
    }
    __syncthreads();
    for (int i = tid; i < NBMAX; i += 256)
        if (hist[i] > 0) base[i] = atomicAdd(&bucket_fill[i], hist[i]);
    __syncthreads();
#pragma unroll
    for (int i = 0; i < 8; ++i) {
        if (i < cnt) {
            int bi = bk[i];
            int r = atomicAdd(&cur[bi], 1) + base[bi];
            if (r < BCAP) pairs[(size_t)bi * BCAP + r] = pk[i];
        }
    }
}

// ---------------------------------------------------------------------------
// CSR pass 2: one block per 128-node bucket (782) [R7 geometry, R9 vec].
// ---------------------------------------------------------------------------
__global__ __launch_bounds__(256) void csr_p2_kernel(const int* __restrict__ bucket_fill,
                                                     const unsigned* __restrict__ pairs,
                                                     const float* __restrict__ x,
                                                     int* __restrict__ rowstart,
                                                     float* __restrict__ dinv,
                                                     int* __restrict__ csr_src,
                                                     __half2* __restrict__ xs_h,
                                                     int N, int nbuck) {
    __shared__ int cnt[BSZ], excl[BSZ], cur[BSZ];
    __shared__ int s1[256];
    const int tid = threadIdx.x;
    const int b = blockIdx.x;
    const int node0 = b << BSH;
    const int nodes_b = min(BSZ, N - node0);

    if (tid < BSZ) { cnt[tid] = 0; cur[tid] = 0; }
    int part = 0;
    for (int j = tid; j < b; j += 256) part += bucket_fill[j];
    s1[tid] = part;
    __syncthreads();
    for (int off = 128; off > 0; off >>= 1) {
        if (tid < off) s1[tid] += s1[tid + off];
        __syncthreads();
    }
    const int bbase = s1[0];
    const int ne = bucket_fill[b];
    __syncthreads();

    const unsigned* bp = pairs + (size_t)b * BCAP;
    for (int i = tid; i < ne; i += 256)
        atomicAdd(&cnt[bp[i] & (BSZ - 1)], 1);
    __syncthreads();
    int c = (tid < BSZ) ? cnt[tid] : 0;
    if (tid < BSZ) s1[tid] = c;
    __syncthreads();
    for (int off = 1; off < BSZ; off <<= 1) {
        int t = (tid < BSZ && tid >= off) ? s1[tid - off] : 0;
        __syncthreads();
        if (tid < BSZ) s1[tid] += t;
        __syncthreads();
    }
    if (tid < BSZ) excl[tid] = s1[tid] - c;
    __syncthreads();

    if (tid < nodes_b) {
        rowstart[node0 + tid] = bbase + excl[tid];
        dinv[node0 + tid] = rsqrtf((float)cnt[tid] + 1.0f);
    }
    if (b == nbuck - 1 && tid == 0) rowstart[N] = bbase + ne;

    // x (f32) -> xs_h (f16, dinv-prescaled): 16 float4 per node
    for (int i = tid; i < nodes_b * 16; i += 256) {
        int ln = i >> 4;
        float d = rsqrtf((float)cnt[ln] + 1.0f);
        float4 v = ((const float4*)x)[(size_t)node0 * 16 + i];
        half4t hh;
        hh[0] = (_Float16)(v.x * d);
        hh[1] = (_Float16)(v.y * d);
        hh[2] = (_Float16)(v.z * d);
        hh[3] = (_Float16)(v.w * d);
        *(half4t*)&xs_h[((size_t)node0 * 16 + i) * 2] = hh;
    }
    for (int i = tid; i < ne; i += 256) {
        unsigned p = bp[i];
        int d = (int)(p & (BSZ - 1));
        int r = atomicAdd(&cur[d], 1);
        csr_src[bbase + excl[d] + r] = (int)(p >> BSH);
    }
}

// ---------------------------------------------------------------------------
// FUSED layer-1: gather (F=64) + GEMM + bias + ReLU + dinv prescale.
// 16-row/256-thread tiles (25000 gather waves x 4 serial nodes). W1t is
// staged into LDS at kernel entry via global_load_lds (no VGPRs held,
// latency hides under the gather). LDS = 20.7 KB. [round-6 proven]
// ---------------------------------------------------------------------------
__global__ __launch_bounds__(256) void gather_gemm1_kernel(
        const __half2* __restrict__ xs,        // [N][32] half2, prescaled by dinv
        const float* __restrict__ dinv,
        const int* __restrict__ rowstart,
        const int* __restrict__ csr_src,
        const _Float16* __restrict__ Wt,       // W1t [128][72]
        const float* __restrict__ bias,        // b1 [128]
        _Float16* __restrict__ Out, int N) {   // a1 [N][128]
    constexpr int KP = 72;
    __shared__ _Float16 Wl[128 * KP];          // 18.4 KB staged weights
    __shared__ _Float16 As[16 * KP];           // 2.25 KB gathered tile
    const int tid = threadIdx.x;
    const int lane = tid & 63;
    const int wave = tid >> 6;                 // 0..3
    const int q = lane >> 4;
    const int l15 = lane & 15;

    // ---- Stage W1t -> LDS (18432 B = 18 x 1KB wave-issues), fire & forget
    for (int i = wave; i < 18; i += 4)
        gload_lds16((const char*)Wt + i * 1024 + lane * 16, (char*)Wl + i * 1024);

    const int f2 = lane & 31;
    // ---- Phase 1: each wave gathers 4 nodes (proven gather64 body) ----
    for (int nn = 0; nn < 4; ++nn) {
        const int r = wave * 4 + nn;
        const int node = blockIdx.x * 16 + r;
        if (node < N) {
            int beg = rowstart[node];
            int end = rowstart[node + 1];
            int deg = end - beg;

            float2 self = __half22float2(xs[(size_t)node * 32 + f2]);
            float2 acc;

            if (deg <= 16) {
                int myidx = (lane < deg) ? csr_src[beg + lane] : node;
                float comp = (float)(deg - 15);      // 1 (self) - (16 - deg) pads
                acc.x = self.x * comp;
                acc.y = self.y * comp;
                float2 v[16];
#pragma unroll
                for (int u = 0; u < 16; ++u) {
                    int s = __shfl(myidx, u);
                    v[u] = __half22float2(xs[(size_t)s * 32 + f2]);
                }
#pragma unroll
                for (int u = 0; u < 16; ++u) { acc.x += v[u].x; acc.y += v[u].y; }
            } else {
                int lim = deg < 64 ? deg : 64;
                int myidx = (lane < lim) ? csr_src[beg + lane] : node;
                int itersUp = (lim + 7) & ~7;
                float comp = (float)(1 - (itersUp - lim));
                acc.x = self.x * comp;
                acc.y = self.y * comp;
                for (int j = 0; j < itersUp; j += 8) {
                    int s[8];
#pragma unroll
                    for (int u = 0; u < 8; ++u) s[u] = __shfl(myidx, j + u);
                    float2 v[8];
#pragma unroll
                    for (int u = 0; u < 8; ++u) v[u] = __half22float2(xs[(size_t)s[u] * 32 + f2]);
#pragma unroll
                    for (int u = 0; u < 8; ++u) { acc.x += v[u].x; acc.y += v[u].y; }
                }
                for (int j = beg + 64; j < end; ++j) {
                    float2 v = __half22float2(xs[(size_t)csr_src[j] * 32 + f2]);
                    acc.x += v.x;
                    acc.y += v.y;
                }
            }
            if (lane < 32) {
                float d = dinv[node];
                ((__half2*)As)[r * 36 + f2] = __floats2half2_rn(d * acc.x, d * acc.y);
            }
        }
    }
    __syncthreads();   // also drains the weight staging

    // ---- Phase 2: GEMM 16x64 @ 64x128, + bias + ReLU + dinv, write a1 ----
    half8 xf[2];
#pragma unroll
    for (int c = 0; c < 2; ++c)
        xf[c] = *(const half8*)(As + l15 * KP + c * 32 + q * 8);
    const int myrow = blockIdx.x * 16 + l15;
    float sc = (myrow < N) ? dinv[myrow] : 0.0f;
#pragma unroll
    for (int tt = 0; tt < 2; ++tt) {
        const int t = wave * 2 + tt;
        floatx4 acc = (floatx4){0.f, 0.f, 0.f, 0.f};
#pragma unroll
        for (int c = 0; c < 2; ++c) {
            half8 wf = *(const half8*)(Wl + (t * 16 + l15) * KP + c * 32 + q * 8);
            acc = __builtin_amdgcn_mfma_f32_16x16x32_f16(wf, xf[c], acc, 0, 0, 0);
        }
        if (myrow < N) {
            floatx4 bv = *(const floatx4*)(bias + t * 16 + q * 4);
            const int c0 = t * 16 + q * 4;
            half4t hh;
#pragma unroll
            for (int j = 0; j < 4; ++j)
                hh[j] = (_Float16)(sc * fmaxf(acc[j] + bv[j], 0.0f));
            *(half4t*)(Out + (size_t)myrow * 128 + c0) = hh;
        }
    }
}

// ---------------------------------------------------------------------------
// FUSED layer-2: gather (F=128) + GEMM + ReLU + classifier + log_softmax.
// Round-4 proven body (56.6 us, occupancy 64%): 16-row/256-thread tiles,
// weights read from global post-barrier (L2-hot).
// ---------------------------------------------------------------------------
__global__ __launch_bounds__(256) void gather_gemm_final_kernel(
        const __half2* __restrict__ hs,        // a1, rows of 64 half2
        const float* __restrict__ dinv,
        const int* __restrict__ rowstart,
        const int* __restrict__ csr_src,
        const _Float16* __restrict__ Wt,       // W2t [128][136]
        const float* __restrict__ bias,        // b2 [128]
        const _Float16* __restrict__ Wct,      // [16][136]
        const float* __restrict__ bl,          // [10]
        float* __restrict__ out, int N) {
    constexpr int KP = 136;                    // padded row stride (halves)
    __shared__ _Float16 As[16 * KP];           // gathered tile (4.25 KB)
    __shared__ _Float16 H2[16 * KP];           // relu(As@W2+b2)   (4.25 KB)
    const int tid = threadIdx.x;
    const int lane = tid & 63;
    const int wave = tid >> 6;                 // 0..3

    // ---- Phase 1: each wave gathers 4 nodes (proven gather128 v1 body) ----
    for (int nn = 0; nn < 4; ++nn) {
        const int r = wave * 4 + nn;
        const int node = blockIdx.x * 16 + r;
        if (node < N) {
            int beg = rowstart[node];
            int end = rowstart[node + 1];
            int deg = end - beg;

            float2 self = __half22float2(hs[(size_t)node * 64 + lane]);
            int lim = deg < 64 ? deg : 64;
            int myidx = (lane < lim) ? csr_src[beg + lane] : node;
            int itersUp = (lim + 7) & ~7;
            float comp = (float)(1 - (itersUp - lim));
            float2 acc;
            acc.x = self.x * comp;
            acc.y = self.y * comp;

            for (int j = 0; j < itersUp; j += 8) {
                int s[8];
#pragma unroll
                for (int u = 0; u < 8; ++u) s[u] = __shfl(myidx, j + u);
                float2 v[8];
#pragma unroll
                for (int u = 0; u < 8; ++u) v[u] = __half22float2(hs[(size_t)s[u] * 64 + lane]);
#pragma unroll
                for (int u = 0; u < 8; ++u) { acc.x += v[u].x; acc.y += v[u].y; }
            }
            for (int j = beg + 64; j < end; ++j) {
                float2 v = __half22float2(hs[(size_t)csr_src[j] * 64 + lane]);
                acc.x += v.x;
                acc.y += v.y;
            }
            float d = dinv[node];
            ((__half2*)As)[r * 68 + lane] = __floats2half2_rn(d * acc.x, d * acc.y);
        }
    }
    __syncthreads();

    // ---- Phase 2: GEMM1 (16 rows x 128 cols). Wave w owns col-tiles 2w, 2w+1. ----
    const int q = lane >> 4;
    const int l15 = lane & 15;

    half8 xf[4];
#pragma unroll
    for (int c = 0; c < 4; ++c)
        xf[c] = *(const half8*)(As + l15 * KP + c * 32 + q * 8);

#pragma unroll
    for (int tt = 0; tt < 2; ++tt) {
        const int t = wave * 2 + tt;
        floatx4 acc = (floatx4){0.f, 0.f, 0.f, 0.f};
#pragma unroll
        for (int c = 0; c < 4; ++c) {
            half8 wf = *(const half8*)(Wt + (t * 16 + l15) * KP + c * 32 + q * 8);
            acc = __builtin_amdgcn_mfma_f32_16x16x32_f16(wf, xf[c], acc, 0, 0, 0);
        }
        const int c0 = t * 16 + q * 4;
        floatx4 bv = *(const floatx4*)(bias + c0);
        half4t hh;
#pragma unroll
        for (int j = 0; j < 4; ++j)
            hh[j] = (_Float16)fmaxf(acc[j] + bv[j], 0.0f);
        *(half4t*)&H2[l15 * KP + c0] = hh;
    }
    __syncthreads();

    // ---- Phase 3: classifier + log_softmax (wave 0; tiny) ----
    if (wave == 0) {
        floatx4 lg = (floatx4){0.f, 0.f, 0.f, 0.f};
#pragma unroll
        for (int c = 0; c < 4; ++c) {
            half8 wcf = *(const half8*)(Wct + l15 * KP + c * 32 + q * 8);
            half8 af = *(const half8*)(H2 + l15 * KP + c * 32 + q * 8);
            lg = __builtin_amdgcn_mfma_f32_16x16x32_f16(wcf, af, lg, 0, 0, 0);
        }
        const int myrow = blockIdx.x * 16 + l15;
        if (myrow < N) {
            float v[4];
#pragma unroll
            for (int reg = 0; reg < 4; ++reg) {
                int cls = q * 4 + reg;
                v[reg] = lg[reg] + ((cls < NUM_CLASSES) ? bl[cls] : -1e30f);
            }
            float mx = fmaxf(fmaxf(v[0], v[1]), fmaxf(v[2], v[3]));
            mx = fmaxf(mx, __shfl_xor(mx, 16));
            mx = fmaxf(mx, __shfl_xor(mx, 32));
            float sm = expf(v[0] - mx) + expf(v[1] - mx) + expf(v[2] - mx) + expf(v[3] - mx);
            sm += __shfl_xor(sm, 16);
            sm += __shfl_xor(sm, 32);
            float lse = mx + logf(sm);
#pragma unroll
            for (int reg = 0; reg < 4; ++reg) {
                int cls = q * 4 + reg;
                if (cls < NUM_CLASSES)
                    out[(size_t)myrow * NUM_CLASSES + cls] = v[reg] - lse;
            }
        }
    }
}

// ---------------------------------------------------------------------------
// Launch
// ---------------------------------------------------------------------------
extern "C" void kernel_launch(void* const* d_in, const int* in_sizes, int n_in,
                              void* d_out, int out_size, void* d_ws, size_t ws_size,
                              hipStream_t stream) {
    const float* x  = (const float*)d_in[0];
    const int*   ei = (const int*)d_in[1];
    const float* W1 = (const float*)d_in[2];
    const float* b1 = (const float*)d_in[3];
    const float* W2 = (const float*)d_in[4];
    const float* b2 = (const float*)d_in[5];
    const float* Wlc = (const float*)d_in[6];
    const float* bl = (const float*)d_in[7];
    float* out = (float*)d_out;

    const int N = in_sizes[0] / 64;         // 100000
    const int E = in_sizes[1] / 2;          // 1000000
    const int* src = ei;
    const int* dst = ei + E;
    const int nbuck = (N + BSZ - 1) >> BSH; // 782

    char* ws = (char*)d_ws;
    int*      bucket_fill = (int*)(ws + 0);              // 4 KB
    int*      rowstart    = (int*)(ws + 16384);          // ~400 KB
    float*    dinv        = (float*)(ws + 524288);       // 400 KB
    _Float16* W1t         = (_Float16*)(ws + 1048576);   // 18.4 KB
    _Float16* W2t         = (_Float16*)(ws + 1069056);   // 34.8 KB
    _Float16* Wct         = (_Float16*)(ws + 1103872);   // 4.4 KB
    unsigned* pairs       = (unsigned*)(ws + 2097152);   // 5.6 MB
    int*      csr_src     = (int*)(ws + 12582912);       // 4 MB
    __half2*  xs_h        = (__half2*)(ws + 16777216);   // 12.8 MB
    __half2*  a1_h        = (__half2*)(ws + 73400320);   // 25.6 MB

    const int P1B = (E + P1BATCH - 1) / P1BATCH;   // 489
    const int F1B = (N + 15) / 16;                 // 6250 fused 16-row tiles

    // --- CSR build front-end (merged prep + direct-scatter p1) ---
    hipMemsetAsync(bucket_fill, 0, nbuck * sizeof(int), stream);
    prep_p1_kernel<<<PREPB + P1B, 256, 0, stream>>>(W1, W2, Wlc, W1t, W2t, Wct,
                                                    src, dst, bucket_fill, pairs, E);
    csr_p2_kernel<<<nbuck, 256, 0, stream>>>(bucket_fill, pairs, x, rowstart, dinv,
                                             csr_src, xs_h, N, nbuck);

    // --- Layer 1: FUSED gather (64 feats) + GEMM + ReLU ---
    gather_gemm1_kernel<<<F1B, 256, 0, stream>>>(xs_h, dinv, rowstart, csr_src,
                                                 W1t, b1, (_Float16*)a1_h, N);

    // --- Layer 2: FUSED gather + GEMM + classifier + log_softmax ---
    gather_gemm_final_kernel<<<F1B, 256, 0, stream>>>(a1_h, dinv, rowstart, csr_src,
                                                      W2t, b2, Wct, bl, out, N);
}

// Round 11
// 205.971 us; speedup vs baseline: 1.0345x; 1.0345x over previous
//
#include <hip/hip_runtime.h>
#include <hip/hip_fp16.h>
#include <math.h>

#define NUM_CLASSES 10

// Bucketed CSR build parameters (128 nodes/bucket -> 782 buckets) [R7 proven]
#define BSH 7
#define BSZ 128            // nodes per bucket
#define BCAP 1792          // max edges per bucket (mean ~1280, sigma ~36; +14 sigma)
#define NBMAX 1024         // static LDS histogram capacity
#define P1BATCH 4096       // edges per p1-role block (16/thread) [R10: 2048 regressed]
#define PREPB 97           // prep-role blocks in the merged kernel

typedef _Float16 half8  __attribute__((ext_vector_type(8)));
typedef _Float16 half4t __attribute__((ext_vector_type(4)));
typedef float    floatx4 __attribute__((ext_vector_type(4)));

// Fire-and-forget 16B global->LDS DMA (no VGPR round-trip). Lane i of the
// wave writes lds_base + i*16; global src is per-lane. Drained by the
// vmcnt(0) the compiler emits before the next __syncthreads().
__device__ __forceinline__ void gload_lds16(const void* g, void* l) {
    __builtin_amdgcn_global_load_lds(
        (const __attribute__((address_space(1))) unsigned int*)g,
        (__attribute__((address_space(3))) unsigned int*)l, 16, 0, 0);
}

// ---------------------------------------------------------------------------
// Merged prep + CSR pass 1 (direct scatter, 12 KB LDS — R7 geometry).
// R9-proven: int4-vectorized edge ingest (8 dwordx4 replaces 32 dword loads
// per thread). 16 edges/thread amortizes fixed phases (R10: halving batch
// cost +5.7 us — per-block fixed cost, not grid starvation, is the limiter).
// ---------------------------------------------------------------------------
__global__ __launch_bounds__(256) void prep_p1_kernel(const float* __restrict__ W1,
                                                      const float* __restrict__ W2,
                                                      const float* __restrict__ Wlc,
                                                      _Float16* __restrict__ W1t,
                                                      _Float16* __restrict__ W2t,
                                                      _Float16* __restrict__ Wct,
                                                      const int* __restrict__ src,
                                                      const int* __restrict__ dst,
                                                      int* __restrict__ bucket_fill,
                                                      unsigned* __restrict__ pairs, int E) {
    __shared__ int hist[NBMAX], base[NBMAX], cur[NBMAX];   // 12 KB
    const int tid = threadIdx.x;
    const int b = blockIdx.x;

    if (b < PREPB) {
        if (b < 32) {
            int i = b * 256 + tid;            // 8192 = 64*128
            int k = i >> 7, c = i & 127;
            W1t[c * 72 + k] = (_Float16)W1[i];
        } else if (b < 96) {
            int i = (b - 32) * 256 + tid;     // 16384 = 128*128
            int k = i >> 7, c = i & 127;
            W2t[c * 136 + k] = (_Float16)W2[i];
        } else {
            for (int i = tid; i < 16 * 136; i += 256) {
                int c = i / 136, k = i - c * 136;
                float v = (c < NUM_CLASSES && k < 128) ? Wlc[k * NUM_CLASSES + c] : 0.0f;
                Wct[i] = (_Float16)v;
            }
        }
        return;
    }

    for (int i = tid; i < NBMAX; i += 256) { hist[i] = 0; cur[i] = 0; }
    __syncthreads();
    const int bb = (b - PREPB) * P1BATCH;
    const int4* src4 = (const int4*)src;
    const int4* dst4 = (const int4*)dst;
    const bool v4ok = ((E & 3) == 0);
    unsigned pk[16];
    int bk[16];
    int cnt = 0;
#pragma unroll
    for (int j = 0; j < 4; ++j) {
        const int g4 = (bb >> 2) + j * 256 + tid;
        const int base4 = g4 << 2;
        if (v4ok && base4 + 3 < E) {
            const int4 s4 = src4[g4];
            const int4 d4 = dst4[g4];
            const int ss[4] = {s4.x, s4.y, s4.z, s4.w};
            const int dd[4] = {d4.x, d4.y, d4.z, d4.w};
#pragma unroll
            for (int u = 0; u < 4; ++u) {
                bk[j * 4 + u] = dd[u] >> BSH;
                pk[j * 4 + u] = ((unsigned)ss[u] << BSH) | (unsigned)(dd[u] & (BSZ - 1));
                atomicAdd(&hist[bk[j * 4 + u]], 1);
            }
            cnt = j * 4 + 4;
        } else {
#pragma unroll
            for (int u = 0; u < 4; ++u) {
                const int idx = base4 + u;
                if (idx < E) {
                    int s = src[idx], d = dst[idx];
                    bk[j * 4 + u] = d >> BSH;
                    pk[j * 4 + u] = ((unsigned)s << BSH) | (unsigned)(d & (BSZ - 1));
                    atomicAdd(&hist[bk[j * 4 + u]], 1);
                    cnt = j * 4 + u + 1;
                }
            }
        }
    }
    __syncthreads();
    for (int i = tid; i < NBMAX; i += 256)
        if (hist[i] > 0) base[i] = atomicAdd(&bucket_fill[i], hist[i]);
    __syncthreads();
#pragma unroll
    for (int i = 0; i < 16; ++i) {
        if (i < cnt) {
            int bi = bk[i];
            int r = atomicAdd(&cur[bi], 1) + base[bi];
            if (r < BCAP) pairs[(size_t)bi * BCAP + r] = pk[i];
        }
    }
}

// ---------------------------------------------------------------------------
// CSR pass 2: one block per 128-node bucket (782) [R7 geometry, R9 vec].
// ---------------------------------------------------------------------------
__global__ __launch_bounds__(256) void csr_p2_kernel(const int* __restrict__ bucket_fill,
                                                     const unsigned* __restrict__ pairs,
                                                     const float* __restrict__ x,
                                                     int* __restrict__ rowstart,
                                                     float* __restrict__ dinv,
                                                     int* __restrict__ csr_src,
                                                     __half2* __restrict__ xs_h,
                                                     int N, int nbuck) {
    __shared__ int cnt[BSZ], excl[BSZ], cur[BSZ];
    __shared__ int s1[256];
    const int tid = threadIdx.x;
    const int b = blockIdx.x;
    const int node0 = b << BSH;
    const int nodes_b = min(BSZ, N - node0);

    if (tid < BSZ) { cnt[tid] = 0; cur[tid] = 0; }
    int part = 0;
    for (int j = tid; j < b; j += 256) part += bucket_fill[j];
    s1[tid] = part;
    __syncthreads();
    for (int off = 128; off > 0; off >>= 1) {
        if (tid < off) s1[tid] += s1[tid + off];
        __syncthreads();
    }
    const int bbase = s1[0];
    const int ne = bucket_fill[b];
    __syncthreads();

    const unsigned* bp = pairs + (size_t)b * BCAP;
    for (int i = tid; i < ne; i += 256)
        atomicAdd(&cnt[bp[i] & (BSZ - 1)], 1);
    __syncthreads();
    int c = (tid < BSZ) ? cnt[tid] : 0;
    if (tid < BSZ) s1[tid] = c;
    __syncthreads();
    for (int off = 1; off < BSZ; off <<= 1) {
        int t = (tid < BSZ && tid >= off) ? s1[tid - off] : 0;
        __syncthreads();
        if (tid < BSZ) s1[tid] += t;
        __syncthreads();
    }
    if (tid < BSZ) excl[tid] = s1[tid] - c;
    __syncthreads();

    if (tid < nodes_b) {
        rowstart[node0 + tid] = bbase + excl[tid];
        dinv[node0 + tid] = rsqrtf((float)cnt[tid] + 1.0f);
    }
    if (b == nbuck - 1 && tid == 0) rowstart[N] = bbase + ne;

    // x (f32) -> xs_h (f16, dinv-prescaled): 16 float4 per node
    for (int i = tid; i < nodes_b * 16; i += 256) {
        int ln = i >> 4;
        float d = rsqrtf((float)cnt[ln] + 1.0f);
        float4 v = ((const float4*)x)[(size_t)node0 * 16 + i];
        half4t hh;
        hh[0] = (_Float16)(v.x * d);
        hh[1] = (_Float16)(v.y * d);
        hh[2] = (_Float16)(v.z * d);
        hh[3] = (_Float16)(v.w * d);
        *(half4t*)&xs_h[((size_t)node0 * 16 + i) * 2] = hh;
    }
    for (int i = tid; i < ne; i += 256) {
        unsigned p = bp[i];
        int d = (int)(p & (BSZ - 1));
        int r = atomicAdd(&cur[d], 1);
        csr_src[bbase + excl[d] + r] = (int)(p >> BSH);
    }
}

// ---------------------------------------------------------------------------
// FUSED layer-1: gather (F=64) + GEMM + bias + ReLU + dinv prescale.
// 16-row/256-thread tiles (25000 gather waves x 4 serial nodes). W1t is
// staged into LDS at kernel entry via global_load_lds (no VGPRs held,
// latency hides under the gather). LDS = 20.7 KB. [round-6 proven]
// ---------------------------------------------------------------------------
__global__ __launch_bounds__(256) void gather_gemm1_kernel(
        const __half2* __restrict__ xs,        // [N][32] half2, prescaled by dinv
        const float* __restrict__ dinv,
        const int* __restrict__ rowstart,
        const int* __restrict__ csr_src,
        const _Float16* __restrict__ Wt,       // W1t [128][72]
        const float* __restrict__ bias,        // b1 [128]
        _Float16* __restrict__ Out, int N) {   // a1 [N][128]
    constexpr int KP = 72;
    __shared__ _Float16 Wl[128 * KP];          // 18.4 KB staged weights
    __shared__ _Float16 As[16 * KP];           // 2.25 KB gathered tile
    const int tid = threadIdx.x;
    const int lane = tid & 63;
    const int wave = tid >> 6;                 // 0..3
    const int q = lane >> 4;
    const int l15 = lane & 15;

    // ---- Stage W1t -> LDS (18432 B = 18 x 1KB wave-issues), fire & forget
    for (int i = wave; i < 18; i += 4)
        gload_lds16((const char*)Wt + i * 1024 + lane * 16, (char*)Wl + i * 1024);

    const int f2 = lane & 31;
    // ---- Phase 1: each wave gathers 4 nodes (proven gather64 body) ----
    for (int nn = 0; nn < 4; ++nn) {
        const int r = wave * 4 + nn;
        const int node = blockIdx.x * 16 + r;
        if (node < N) {
            int beg = rowstart[node];
            int end = rowstart[node + 1];
            int deg = end - beg;

            float2 self = __half22float2(xs[(size_t)node * 32 + f2]);
            float2 acc;

            if (deg <= 16) {
                int myidx = (lane < deg) ? csr_src[beg + lane] : node;
                float comp = (float)(deg - 15);      // 1 (self) - (16 - deg) pads
                acc.x = self.x * comp;
                acc.y = self.y * comp;
                float2 v[16];
#pragma unroll
                for (int u = 0; u < 16; ++u) {
                    int s = __shfl(myidx, u);
                    v[u] = __half22float2(xs[(size_t)s * 32 + f2]);
                }
#pragma unroll
                for (int u = 0; u < 16; ++u) { acc.x += v[u].x; acc.y += v[u].y; }
            } else {
                int lim = deg < 64 ? deg : 64;
                int myidx = (lane < lim) ? csr_src[beg + lane] : node;
                int itersUp = (lim + 7) & ~7;
                float comp = (float)(1 - (itersUp - lim));
                acc.x = self.x * comp;
                acc.y = self.y * comp;
                for (int j = 0; j < itersUp; j += 8) {
                    int s[8];
#pragma unroll
                    for (int u = 0; u < 8; ++u) s[u] = __shfl(myidx, j + u);
                    float2 v[8];
#pragma unroll
                    for (int u = 0; u < 8; ++u) v[u] = __half22float2(xs[(size_t)s[u] * 32 + f2]);
#pragma unroll
                    for (int u = 0; u < 8; ++u) { acc.x += v[u].x; acc.y += v[u].y; }
                }
                for (int j = beg + 64; j < end; ++j) {
                    float2 v = __half22float2(xs[(size_t)csr_src[j] * 32 + f2]);
                    acc.x += v.x;
                    acc.y += v.y;
                }
            }
            if (lane < 32) {
                float d = dinv[node];
                ((__half2*)As)[r * 36 + f2] = __floats2half2_rn(d * acc.x, d * acc.y);
            }
        }
    }
    __syncthreads();   // also drains the weight staging

    // ---- Phase 2: GEMM 16x64 @ 64x128, + bias + ReLU + dinv, write a1 ----
    half8 xf[2];
#pragma unroll
    for (int c = 0; c < 2; ++c)
        xf[c] = *(const half8*)(As + l15 * KP + c * 32 + q * 8);
    const int myrow = blockIdx.x * 16 + l15;
    float sc = (myrow < N) ? dinv[myrow] : 0.0f;
#pragma unroll
    for (int tt = 0; tt < 2; ++tt) {
        const int t = wave * 2 + tt;
        floatx4 acc = (floatx4){0.f, 0.f, 0.f, 0.f};
#pragma unroll
        for (int c = 0; c < 2; ++c) {
            half8 wf = *(const half8*)(Wl + (t * 16 + l15) * KP + c * 32 + q * 8);
            acc = __builtin_amdgcn_mfma_f32_16x16x32_f16(wf, xf[c], acc, 0, 0, 0);
        }
        if (myrow < N) {
            floatx4 bv = *(const floatx4*)(bias + t * 16 + q * 4);
            const int c0 = t * 16 + q * 4;
            half4t hh;
#pragma unroll
            for (int j = 0; j < 4; ++j)
                hh[j] = (_Float16)(sc * fmaxf(acc[j] + bv[j], 0.0f));
            *(half4t*)(Out + (size_t)myrow * 128 + c0) = hh;
        }
    }
}

// ---------------------------------------------------------------------------
// FUSED layer-2: gather (F=128) + GEMM + ReLU + classifier + log_softmax.
// Round-4 proven body (56.6 us, occupancy 64%): 16-row/256-thread tiles,
// weights read from global post-barrier (L2-hot). Warm-cache dispatches run
// at identical duration with FETCH=0 -> LLC/fabric random-line bound.
// ---------------------------------------------------------------------------
__global__ __launch_bounds__(256) void gather_gemm_final_kernel(
        const __half2* __restrict__ hs,        // a1, rows of 64 half2
        const float* __restrict__ dinv,
        const int* __restrict__ rowstart,
        const int* __restrict__ csr_src,
        const _Float16* __restrict__ Wt,       // W2t [128][136]
        const float* __restrict__ bias,        // b2 [128]
        const _Float16* __restrict__ Wct,      // [16][136]
        const float* __restrict__ bl,          // [10]
        float* __restrict__ out, int N) {
    constexpr int KP = 136;                    // padded row stride (halves)
    __shared__ _Float16 As[16 * KP];           // gathered tile (4.25 KB)
    __shared__ _Float16 H2[16 * KP];           // relu(As@W2+b2)   (4.25 KB)
    const int tid = threadIdx.x;
    const int lane = tid & 63;
    const int wave = tid >> 6;                 // 0..3

    // ---- Phase 1: each wave gathers 4 nodes (proven gather128 v1 body) ----
    for (int nn = 0; nn < 4; ++nn) {
        const int r = wave * 4 + nn;
        const int node = blockIdx.x * 16 + r;
        if (node < N) {
            int beg = rowstart[node];
            int end = rowstart[node + 1];
            int deg = end - beg;

            float2 self = __half22float2(hs[(size_t)node * 64 + lane]);
            int lim = deg < 64 ? deg : 64;
            int myidx = (lane < lim) ? csr_src[beg + lane] : node;
            int itersUp = (lim + 7) & ~7;
            float comp = (float)(1 - (itersUp - lim));
            float2 acc;
            acc.x = self.x * comp;
            acc.y = self.y * comp;

            for (int j = 0; j < itersUp; j += 8) {
                int s[8];
#pragma unroll
                for (int u = 0; u < 8; ++u) s[u] = __shfl(myidx, j + u);
                float2 v[8];
#pragma unroll
                for (int u = 0; u < 8; ++u) v[u] = __half22float2(hs[(size_t)s[u] * 64 + lane]);
#pragma unroll
                for (int u = 0; u < 8; ++u) { acc.x += v[u].x; acc.y += v[u].y; }
            }
            for (int j = beg + 64; j < end; ++j) {
                float2 v = __half22float2(hs[(size_t)csr_src[j] * 64 + lane]);
                acc.x += v.x;
                acc.y += v.y;
            }
            float d = dinv[node];
            ((__half2*)As)[r * 68 + lane] = __floats2half2_rn(d * acc.x, d * acc.y);
        }
    }
    __syncthreads();

    // ---- Phase 2: GEMM1 (16 rows x 128 cols). Wave w owns col-tiles 2w, 2w+1. ----
    const int q = lane >> 4;
    const int l15 = lane & 15;

    half8 xf[4];
#pragma unroll
    for (int c = 0; c < 4; ++c)
        xf[c] = *(const half8*)(As + l15 * KP + c * 32 + q * 8);

#pragma unroll
    for (int tt = 0; tt < 2; ++tt) {
        const int t = wave * 2 + tt;
        floatx4 acc = (floatx4){0.f, 0.f, 0.f, 0.f};
#pragma unroll
        for (int c = 0; c < 4; ++c) {
            half8 wf = *(const half8*)(Wt + (t * 16 + l15) * KP + c * 32 + q * 8);
            acc = __builtin_amdgcn_mfma_f32_16x16x32_f16(wf, xf[c], acc, 0, 0, 0);
        }
        const int c0 = t * 16 + q * 4;
        floatx4 bv = *(const floatx4*)(bias + c0);
        half4t hh;
#pragma unroll
        for (int j = 0; j < 4; ++j)
            hh[j] = (_Float16)fmaxf(acc[j] + bv[j], 0.0f);
        *(half4t*)&H2[l15 * KP + c0] = hh;
    }
    __syncthreads();

    // ---- Phase 3: classifier + log_softmax (wave 0; tiny) ----
    if (wave == 0) {
        floatx4 lg = (floatx4){0.f, 0.f, 0.f, 0.f};
#pragma unroll
        for (int c = 0; c < 4; ++c) {
            half8 wcf = *(const half8*)(Wct + l15 * KP + c * 32 + q * 8);
            half8 af = *(const half8*)(H2 + l15 * KP + c * 32 + q * 8);
            lg = __builtin_amdgcn_mfma_f32_16x16x32_f16(wcf, af, lg, 0, 0, 0);
        }
        const int myrow = blockIdx.x * 16 + l15;
        if (myrow < N) {
            float v[4];
#pragma unroll
            for (int reg = 0; reg < 4; ++reg) {
                int cls = q * 4 + reg;
                v[reg] = lg[reg] + ((cls < NUM_CLASSES) ? bl[cls] : -1e30f);
            }
            float mx = fmaxf(fmaxf(v[0], v[1]), fmaxf(v[2], v[3]));
            mx = fmaxf(mx, __shfl_xor(mx, 16));
            mx = fmaxf(mx, __shfl_xor(mx, 32));
            float sm = expf(v[0] - mx) + expf(v[1] - mx) + expf(v[2] - mx) + expf(v[3] - mx);
            sm += __shfl_xor(sm, 16);
            sm += __shfl_xor(sm, 32);
            float lse = mx + logf(sm);
#pragma unroll
            for (int reg = 0; reg < 4; ++reg) {
                int cls = q * 4 + reg;
                if (cls < NUM_CLASSES)
                    out[(size_t)myrow * NUM_CLASSES + cls] = v[reg] - lse;
            }
        }
    }
}

// ---------------------------------------------------------------------------
// Launch
// ---------------------------------------------------------------------------
extern "C" void kernel_launch(void* const* d_in, const int* in_sizes, int n_in,
                              void* d_out, int out_size, void* d_ws, size_t ws_size,
                              hipStream_t stream) {
    const float* x  = (const float*)d_in[0];
    const int*   ei = (const int*)d_in[1];
    const float* W1 = (const float*)d_in[2];
    const float* b1 = (const float*)d_in[3];
    const float* W2 = (const float*)d_in[4];
    const float* b2 = (const float*)d_in[5];
    const float* Wlc = (const float*)d_in[6];
    const float* bl = (const float*)d_in[7];
    float* out = (float*)d_out;

    const int N = in_sizes[0] / 64;         // 100000
    const int E = in_sizes[1] / 2;          // 1000000
    const int* src = ei;
    const int* dst = ei + E;
    const int nbuck = (N + BSZ - 1) >> BSH; // 782

    char* ws = (char*)d_ws;
    int*      bucket_fill = (int*)(ws + 0);              // 4 KB
    int*      rowstart    = (int*)(ws + 16384);          // ~400 KB
    float*    dinv        = (float*)(ws + 524288);       // 400 KB
    _Float16* W1t         = (_Float16*)(ws + 1048576);   // 18.4 KB
    _Float16* W2t         = (_Float16*)(ws + 1069056);   // 34.8 KB
    _Float16* Wct         = (_Float16*)(ws + 1103872);   // 4.4 KB
    unsigned* pairs       = (unsigned*)(ws + 2097152);   // 5.6 MB
    int*      csr_src     = (int*)(ws + 12582912);       // 4 MB
    __half2*  xs_h        = (__half2*)(ws + 16777216);   // 12.8 MB
    __half2*  a1_h        = (__half2*)(ws + 73400320);   // 25.6 MB

    const int P1B = (E + P1BATCH - 1) / P1BATCH;   // 245
    const int F1B = (N + 15) / 16;                 // 6250 fused 16-row tiles

    // --- CSR build front-end (merged prep + direct-scatter p1) ---
    hipMemsetAsync(bucket_fill, 0, nbuck * sizeof(int), stream);
    prep_p1_kernel<<<PREPB + P1B, 256, 0, stream>>>(W1, W2, Wlc, W1t, W2t, Wct,
                                                    src, dst, bucket_fill, pairs, E);
    csr_p2_kernel<<<nbuck, 256, 0, stream>>>(bucket_fill, pairs, x, rowstart, dinv,
                                             csr_src, xs_h, N, nbuck);

    // --- Layer 1: FUSED gather (64 feats) + GEMM + ReLU ---
    gather_gemm1_kernel<<<F1B, 256, 0, stream>>>(xs_h, dinv, rowstart, csr_src,
                                                 W1t, b1, (_Float16*)a1_h, N);

    // --- Layer 2: FUSED gather + GEMM + classifier + log_softmax ---
    gather_gemm_final_kernel<<<F1B, 256, 0, stream>>>(a1_h, dinv, rowstart, csr_src,
                                                      W2t, b2, Wct, bl, out, N);
}